// Round 10
// baseline (280.570 us; speedup 1.0000x reference)
//
#include <hip/hip_runtime.h>

#define EMB   1024
#define NHEAD 16
#define HS    64
#define BATCH 4
#define SEQ   2048
#define MTOK  (BATCH*SEQ)   // 8192 tokens

typedef __bf16 bf16;
typedef __bf16 bf16x8 __attribute__((ext_vector_type(8)));
typedef __bf16 bf16x4 __attribute__((ext_vector_type(4)));
typedef float  f32x4  __attribute__((ext_vector_type(4)));
typedef _Float16 f16;
typedef f16 f16x4 __attribute__((ext_vector_type(4)));
typedef f16 f16x8 __attribute__((ext_vector_type(8)));

#define MFMA16(a,b,c)     __builtin_amdgcn_mfma_f32_16x16x32_bf16(a,b,c,0,0,0)
#define MFMA_H32(a,b,c)   __builtin_amdgcn_mfma_f32_16x16x32_f16(a,b,c,0,0,0)
#define MFMA_H16(a,b,c)   __builtin_amdgcn_mfma_f32_16x16x16f16(a,b,c,0,0,0)

#if __has_builtin(__builtin_amdgcn_exp2f)
#define EXP2(x) __builtin_amdgcn_exp2f(x)
#else
#define EXP2(x) exp2f(x)
#endif

// async global->LDS, 16B per lane; LDS dest = wave-uniform base + lane*16
#define GLL(g, l) __builtin_amdgcn_global_load_lds(                         \
        (const __attribute__((address_space(1))) void*)(g),                 \
        (__attribute__((address_space(3))) void*)(l), 16, 0, 0)

// ---------------- Stage 0: x convert + 4x weight transpose, one launch ------
__global__ __launch_bounds__(256) void k_prep(
        const float* __restrict__ x, bf16* __restrict__ xb,
        const float* __restrict__ W0, const float* __restrict__ W1,
        const float* __restrict__ W2, const float* __restrict__ W3,
        bf16* __restrict__ T0, bf16* __restrict__ T1,
        bf16* __restrict__ T2, bf16* __restrict__ T3) {
    const int z = blockIdx.z;
    if (z == 0) {                      // x fp32 -> bf16 (8M elements)
        const int blk = blockIdx.y * 16 + blockIdx.x;
        const size_t base = (size_t)blk * 32768;
        for (int j = threadIdx.x; j < 8192; j += 256) {
            size_t i = base + (size_t)j * 4;
            float4 v = *(const float4*)(x + i);
            bf16x4 o;
            o[0] = (bf16)v.x; o[1] = (bf16)v.y; o[2] = (bf16)v.z; o[3] = (bf16)v.w;
            *(bf16x4*)(xb + i) = o;
        }
        return;
    }
    __shared__ float tile[64][65];
    const float* W = (z == 1) ? W0 : (z == 2) ? W1 : (z == 3) ? W2 : W3;
    bf16* Wt = (z == 1) ? T0 : (z == 2) ? T1 : (z == 3) ? T2 : T3;
    int c0 = blockIdx.x * 64, r0 = blockIdx.y * 64;
    int tx = threadIdx.x & 63, ty = threadIdx.x >> 6;
    #pragma unroll
    for (int r = ty; r < 64; r += 4)
        tile[r][tx] = W[(r0 + r) * EMB + c0 + tx];
    __syncthreads();
    #pragma unroll
    for (int cc = ty; cc < 64; cc += 4)
        Wt[(c0 + cc) * EMB + r0 + tx] = (bf16)tile[tx][cc];
}

// ---------------- Stage 1: fused QKV GEMM, 256x192 tile, BK=32 --------------
// Q|K|V fused as one N=3072 GEMM, grid 32x16 = 512 blocks = exactly 2/CU.
// LDS 2x(16K A + 12K B) = 56KB. Waves 4Mx2N (64x96, acc[4][6]).
// Window schedule = round-5 proven structure (0 conflicts).
__global__ __launch_bounds__(512, 2) void k_qkv_gemm(
        const bf16* __restrict__ xb,
        const bf16* __restrict__ Wall,   // [3072][1024] = Wq^T | Wk^T | Wv^T
        const float* __restrict__ bq, const float* __restrict__ bk, const float* __restrict__ bv,
        f16* __restrict__ Q, f16* __restrict__ K, f16* __restrict__ Vt) {
    __shared__ __align__(16) bf16 As[2][8192];   // 2 x 16 KB (256 x 32)
    __shared__ __align__(16) bf16 Bs[2][6144];   // 2 x 12 KB (192 x 32)
    const int tid = threadIdx.x;
    const int lane = tid & 63;
    const int l15 = lane & 15, quad = lane >> 4;
    const int wave = tid >> 6;            // 0..7
    const int wm4 = wave & 3;             // M quarter: rows wm4*64..+63
    const int wn2 = wave >> 2;            // N half:   cols wn2*96..+95

    const int mt = blockIdx.x;            // 0..31 (x-major: B panel reused)
    const int nt = blockIdx.y;            // 0..15
    const int n0 = nt * 192;              // in [0,3072)

    const bf16* Abase = xb   + (size_t)mt * 256 * EMB;
    const bf16* Bbase = Wall + (size_t)n0 * EMB;

    // staging source swizzle: chunk n: pair-row P=n>>3, slot s=n&7 holds
    // source chunk c=s^(P&7) -> row 2P+(c>>2), k-chunk c&3.
    const int P   = tid >> 3, s8 = tid & 7;
    const int cch = s8 ^ (P & 7);
    const int r_  = 2 * P + (cch >> 2);
    const int kc8 = (cch & 3) * 8;
    const bf16* Asrc = Abase + (size_t)r_ * EMB + kc8;
    const bf16* Bsrc = Bbase + (size_t)r_ * EMB + kc8;

#define STAGE_A(T, cb) do {                                                  \
    GLL(Asrc + (T) * 32,             &As[cb][tid * 8]);                      \
    GLL(Asrc + 128 * EMB + (T) * 32, &As[cb][tid * 8 + 4096]); } while (0)
#define STAGE_B(T, cb) do {                                                  \
    GLL(Bsrc + (T) * 32,             &Bs[cb][tid * 8]);                      \
    if (tid < 256)                                                           \
        GLL(Bsrc + 128 * EMB + (T) * 32, &Bs[cb][tid * 8 + 4096]);           \
} while (0)

    // read offsets: frag row -> pair P=row>>1, h=row&1; slot (h*4+quad)^(P&7)
    int aoff[4], boff[6];
    #pragma unroll
    for (int mf = 0; mf < 4; mf++) {
        const int row = wm4 * 64 + mf * 16 + l15;
        const int Pr = row >> 1, hh = row & 1;
        aoff[mf] = Pr * 64 + ((((hh << 2) | quad)) ^ (Pr & 7)) * 8;
    }
    #pragma unroll
    for (int nf = 0; nf < 6; nf++) {
        const int row = wn2 * 96 + nf * 16 + l15;
        const int Pr = row >> 1, hh = row & 1;
        boff[nf] = Pr * 64 + ((((hh << 2) | quad)) ^ (Pr & 7)) * 8;
    }

    f32x4 acc[4][6];
    #pragma unroll
    for (int i = 0; i < 4; i++)
        #pragma unroll
        for (int j = 0; j < 6; j++) acc[i][j] = (f32x4){0.f, 0.f, 0.f, 0.f};

#define BARX __builtin_amdgcn_s_barrier()
#define PRI1 __builtin_amdgcn_s_setprio(1)
#define PRI0 __builtin_amdgcn_s_setprio(0)
#define SCHB __builtin_amdgcn_sched_barrier(0)
#define VM0 asm volatile("s_waitcnt vmcnt(0)" ::: "memory")

    // prologue: tile 0 into buf 0
    STAGE_A(0, 0); STAGE_B(0, 0);
    SCHB; VM0; BARX;

    bf16x8 a[4], b[3], b2[3];
    #pragma unroll 1
    for (int W = 0; W < 31; ++W) {
        const int c = W & 1;
        const bf16* Ab = As[c];
        const bf16* Bb = Bs[c];
        #pragma unroll
        for (int i = 0; i < 4; i++) a[i] = *(const bf16x8*)(Ab + aoff[i]);
        #pragma unroll
        for (int j = 0; j < 3; j++) b[j] = *(const bf16x8*)(Bb + boff[j]);
        STAGE_A(W + 1, c ^ 1);
        SCHB;
        BARX; PRI1;
        #pragma unroll
        for (int i = 0; i < 4; i++)
            #pragma unroll
            for (int j = 0; j < 3; j++)
                acc[i][j] = MFMA16(a[i], b[j], acc[i][j]);
        PRI0;
        #pragma unroll
        for (int j = 0; j < 3; j++) b2[j] = *(const bf16x8*)(Bb + boff[3 + j]);
        STAGE_B(W + 1, c ^ 1);
        SCHB; VM0; BARX;        // all waves' stage(W+1) landed; buf-c reads done
        PRI1;
        #pragma unroll
        for (int i = 0; i < 4; i++)
            #pragma unroll
            for (int j = 0; j < 3; j++)
                acc[i][3 + j] = MFMA16(a[i], b2[j], acc[i][3 + j]);
        PRI0;
    }
    {   // W = 31: buf 1, no staging, no gate
        const bf16* Ab = As[1];
        const bf16* Bb = Bs[1];
        #pragma unroll
        for (int i = 0; i < 4; i++) a[i] = *(const bf16x8*)(Ab + aoff[i]);
        #pragma unroll
        for (int j = 0; j < 3; j++) b[j]  = *(const bf16x8*)(Bb + boff[j]);
        #pragma unroll
        for (int j = 0; j < 3; j++) b2[j] = *(const bf16x8*)(Bb + boff[3 + j]);
        #pragma unroll
        for (int i = 0; i < 4; i++)
            #pragma unroll
            for (int j = 0; j < 3; j++) {
                acc[i][j]     = MFMA16(a[i], b[j],  acc[i][j]);
                acc[i][3 + j] = MFMA16(a[i], b2[j], acc[i][3 + j]);
            }
    }
#undef STAGE_A
#undef STAGE_B

    const float QSCALE = 0.18033688011112043f;   // 0.125 * log2(e)
    #pragma unroll
    for (int nf = 0; nf < 6; nf++) {
        const int col = n0 + wn2 * 96 + nf * 16 + l15;   // [0,3072)
        const int whichf = col >> 10;                    // wave-uniform per nf
        const int cc = col & 1023;
        const int h = cc >> 6, d = cc & 63;
        const float bv_ = (whichf == 0) ? bq[cc] : (whichf == 1) ? bk[cc] : bv[cc];
        if (whichf == 2) {
            #pragma unroll
            for (int mf = 0; mf < 4; mf++) {
                const int row0 = mt * 256 + wm4 * 64 + mf * 16 + quad * 4;
                const int b_ = row0 >> 11, tk0 = row0 & (SEQ - 1);
                f16x4 vv;
                #pragma unroll
                for (int r = 0; r < 4; r++) vv[r] = (f16)(acc[mf][nf][r] + bv_);
                *(f16x4*)(Vt + (((size_t)(b_ * NHEAD + h) * 32 + (tk0 >> 6)) * 64 + d) * 64
                          + (tk0 & 63)) = vv;
            }
        } else {
            f16* OUT = (whichf == 0) ? Q : K;
            const float scl = (whichf == 0) ? QSCALE : 1.0f;
            #pragma unroll
            for (int mf = 0; mf < 4; mf++) {
                const int row0 = mt * 256 + wm4 * 64 + mf * 16 + quad * 4;
                const int b_ = row0 >> 11, tk0 = row0 & (SEQ - 1);
                #pragma unroll
                for (int r = 0; r < 4; r++)
                    OUT[((size_t)(b_ * NHEAD + h) * SEQ + (tk0 + r)) * HS + d] =
                        (f16)((acc[mf][nf][r] + bv_) * scl);
            }
        }
    }
}

// ---------------- Stage 2: causal flash attention, S^T trick ----------------
// One q-tile per block, 1024 blocks = exactly 4/CU (ONE dispatch round ->
// wall time = max per-CU work). Round-10: magic-square qt assignment —
// qt = nibble j of 0x0DE3B6587A94C12F (4x4 magic square, every row AND
// column sums 30) — so ANY aligned group-of-4 of j (stride-1 or stride-4
// CU assignment) gives equal per-CU work (68 tile-units, was 56..80).
// bh = xcd*8 + (s&7) unchanged -> XCD-pinned K/V stays L2-resident.
__global__ __launch_bounds__(256) void k_attn(
        const f16* __restrict__ Q, const f16* __restrict__ K,
        const f16* __restrict__ Vt, bf16* __restrict__ y) {
    __shared__ __align__(16) f16 kbuf[2][64 * 64];   // 2 x 8 KB
    __shared__ __align__(16) f16 vbuf[2][64 * 64];   // 2 x 8 KB
    const int tid = threadIdx.x;
    const int wave = tid >> 6, lane = tid & 63;
    const int l15 = lane & 15, quad = lane >> 4;

    const int L = blockIdx.x;
    const int xcd = L & 7, s = L >> 3;
    const int bh = xcd * 8 + (s & 7);
    const int j = s >> 3;                               // 0..15
    const int qt = (int)((0x0DE3B6587A94C12FULL >> (4 * j)) & 15);
    const int h = bh & (NHEAD - 1), b_ = bh >> 4;

    const f16* Qb = Q + (size_t)bh * SEQ * HS;
    const f16* Kb = K + (size_t)bh * SEQ * HS;
    const f16* Vb = Vt + (size_t)bh * 32 * 4096;

    const int c0 = tid, c1 = tid + 256;
    const int soff0 = (c0 >> 3) * 64 + (((c0 & 7) ^ ((c0 >> 3) & 7)) * 8);
    const int soff1 = (c1 >> 3) * 64 + (((c1 & 7) ^ ((c1 >> 3) & 7)) * 8);
    const int swz = l15 & 7;

    f16x4 ones;
    #pragma unroll
    for (int i = 0; i < 4; i++) ones[i] = (f16)1.0f;

    const int ntiles = 2 * qt + 2;
    const int qrow0 = qt * 128 + wave * 32;

    f16x8 qb[2][2];
    #pragma unroll
    for (int qf = 0; qf < 2; qf++)
        #pragma unroll
        for (int dk = 0; dk < 2; dk++)
            qb[qf][dk] = *(const f16x8*)(Qb + (qrow0 + 16 * qf + l15) * HS + 32 * dk + quad * 8);

    f32x4 o[2][4], lacc[2];
    #pragma unroll
    for (int qf = 0; qf < 2; qf++) {
        lacc[qf] = (f32x4){0.f, 0.f, 0.f, 0.f};
        #pragma unroll
        for (int df = 0; df < 4; df++) o[qf][df] = (f32x4){0.f, 0.f, 0.f, 0.f};
    }

    f16x8 kr0 = *(const f16x8*)(Kb + c0 * 8);
    f16x8 kr1 = *(const f16x8*)(Kb + c1 * 8);
    f16x8 vr0 = *(const f16x8*)(Vb + c0 * 8);
    f16x8 vr1 = *(const f16x8*)(Vb + c1 * 8);
    *(f16x8*)(kbuf[0] + soff0) = kr0;
    *(f16x8*)(kbuf[0] + soff1) = kr1;
    *(f16x8*)(vbuf[0] + soff0) = vr0;
    *(f16x8*)(vbuf[0] + soff1) = vr1;

    for (int it = 0; it < ntiles; ++it) {
        const int kv0 = it * 64;
        __syncthreads();
        if (it + 1 < ntiles) {
            const f16* kg = Kb + (size_t)(kv0 + 64) * HS;
            const f16* vg = Vb + (size_t)(it + 1) * 4096;
            kr0 = *(const f16x8*)(kg + c0 * 8);
            kr1 = *(const f16x8*)(kg + c1 * 8);
            vr0 = *(const f16x8*)(vg + c0 * 8);
            vr1 = *(const f16x8*)(vg + c1 * 8);
        }
        if (kv0 <= qrow0 + 31) {
            const f16* kb_ = kbuf[it & 1];
            const f16* vb_ = vbuf[it & 1];

            f32x4 sreg[4][2];
            #pragma unroll
            for (int mb = 0; mb < 4; mb++) {
                f16x8 ka0 = *(const f16x8*)(kb_ + (16 * mb + l15) * 64 + ((quad ^ swz) * 8));
                f16x8 ka1 = *(const f16x8*)(kb_ + (16 * mb + l15) * 64 + (((4 + quad) ^ swz) * 8));
                #pragma unroll
                for (int qf = 0; qf < 2; qf++) {
                    f32x4 t = (f32x4){0.f, 0.f, 0.f, 0.f};
                    t = MFMA_H32(ka0, qb[qf][0], t);
                    t = MFMA_H32(ka1, qb[qf][1], t);
                    sreg[mb][qf] = t;
                }
            }

            f16x4 pa[4][2];
            const bool edge = (kv0 + 63 > qrow0);
            #pragma unroll
            for (int mb = 0; mb < 4; mb++)
                #pragma unroll
                for (int qf = 0; qf < 2; qf++) {
                    f16x4 p;
                    if (edge) {
                        #pragma unroll
                        for (int r = 0; r < 4; r++) {
                            const int kvc = kv0 + 16 * mb + quad * 4 + r;
                            const int qq  = qrow0 + 16 * qf + l15;
                            p[r] = (f16)((kvc <= qq) ? EXP2(sreg[mb][qf][r]) : 0.f);
                        }
                    } else {
                        #pragma unroll
                        for (int r = 0; r < 4; r++)
                            p[r] = (f16)EXP2(sreg[mb][qf][r]);
                    }
                    pa[mb][qf] = p;
                }

            #pragma unroll
            for (int df = 0; df < 4; df++)
                #pragma unroll
                for (int kb = 0; kb < 4; kb++) {
                    f16x4 vfrag = *(const f16x4*)(vb_ + (16 * df + l15) * 64 +
                                    (((2 * kb + (quad >> 1)) ^ swz) * 8) + (quad & 1) * 4);
                    #pragma unroll
                    for (int qf = 0; qf < 2; qf++)
                        o[qf][df] = MFMA_H16(pa[kb][qf], vfrag, o[qf][df]);
                }
            #pragma unroll
            for (int kb = 0; kb < 4; kb++)
                #pragma unroll
                for (int qf = 0; qf < 2; qf++)
                    lacc[qf] = MFMA_H16(pa[kb][qf], ones, lacc[qf]);
        }
        if (it + 1 < ntiles) {
            const int nb = (it + 1) & 1;
            *(f16x8*)(kbuf[nb] + soff0) = kr0;
            *(f16x8*)(kbuf[nb] + soff1) = kr1;
            *(f16x8*)(vbuf[nb] + soff0) = vr0;
            *(f16x8*)(vbuf[nb] + soff1) = vr1;
        }
    }

    #pragma unroll
    for (int qf = 0; qf < 2; qf++)
        #pragma unroll
        for (int r = 0; r < 4; r++) {
            float inv = 1.f / lacc[qf][r];
            int t = qrow0 + 16 * qf + quad * 4 + r;
            bf16* yp = y + ((size_t)(b_ * SEQ + t)) * EMB + h * HS;
            #pragma unroll
            for (int df = 0; df < 4; df++)
                yp[df * 16 + l15] = (bf16)(o[qf][df][r] * inv);
        }
}

// ---------------- Stage 3: out projection (BK=64, swizzled, fp32 out) -------
// REVERTED to the round-7 m97-style loop (round-9 r5-port was +6us: doubling
// the barrier count for 8-MFMA phases costs more than the schedule gains at
// this 128x128/K=1024 shape).
__global__ __launch_bounds__(256) void k_out_gemm(
        const bf16* __restrict__ y, const bf16* __restrict__ Wot,
        const float* __restrict__ bo, float* __restrict__ out) {
    __shared__ __align__(16) bf16 As[128 * 64];
    __shared__ __align__(16) bf16 Bs[128 * 64];
    const int tid = threadIdx.x;
    const int lane = tid & 63;
    const int wave = tid >> 6;
    const int l15 = lane & 15, quad = lane >> 4;
    const int wm = (wave >> 1) * 64, wn = (wave & 1) * 64;
    const int m0 = blockIdx.x * 128;
    const int n0 = blockIdx.y * 128;

    f32x4 acc[4][4];
    #pragma unroll
    for (int i = 0; i < 4; i++)
        #pragma unroll
        for (int j = 0; j < 4; j++) acc[i][j] = (f32x4){0.f, 0.f, 0.f, 0.f};

    const int r0_ = tid >> 3;
    const int kcs = ((tid & 7) ^ (r0_ & 7)) * 8;
    const bf16* Ag = y   + (size_t)m0 * EMB + r0_ * EMB + kcs;
    const bf16* Bg = Wot + (size_t)n0 * EMB + r0_ * EMB + kcs;
    const int rsw = l15 & 7;

    for (int k0 = 0; k0 < EMB; k0 += 64) {
        __syncthreads();
        #pragma unroll
        for (int g = 0; g < 4; g++) {
            GLL(Ag + 32 * g * EMB + k0, As + (tid + g * 256) * 8);
            GLL(Bg + 32 * g * EMB + k0, Bs + (tid + g * 256) * 8);
        }
        __syncthreads();

        bf16x8 af[2][4], bfr[2][4];
        #pragma unroll
        for (int h = 0; h < 2; h++) {
            #pragma unroll
            for (int rf = 0; rf < 4; rf++)
                af[h][rf] = *(const bf16x8*)(As + (wm + rf * 16 + l15) * 64 +
                                             (((4 * h + quad) ^ rsw) * 8));
            #pragma unroll
            for (int cf = 0; cf < 4; cf++)
                bfr[h][cf] = *(const bf16x8*)(Bs + (wn + cf * 16 + l15) * 64 +
                                              (((4 * h + quad) ^ rsw) * 8));
        }
        #pragma unroll
        for (int h = 0; h < 2; h++)
            #pragma unroll
            for (int rf = 0; rf < 4; rf++)
                #pragma unroll
                for (int cf = 0; cf < 4; cf++)
                    acc[rf][cf] = MFMA16(af[h][rf], bfr[h][cf], acc[rf][cf]);
    }

    #pragma unroll
    for (int cf = 0; cf < 4; cf++) {
        const int col = n0 + wn + cf * 16 + l15;
        const float bv_ = bo[col];
        #pragma unroll
        for (int rf = 0; rf < 4; rf++) {
            #pragma unroll
            for (int r = 0; r < 4; r++) {
                const int row = m0 + wm + rf * 16 + quad * 4 + r;
                out[(size_t)row * EMB + col] = acc[rf][cf][r] + bv_;
            }
        }
    }
}

extern "C" void kernel_launch(void* const* d_in, const int* in_sizes, int n_in,
                              void* d_out, int out_size, void* d_ws, size_t ws_size,
                              hipStream_t stream) {
    const float* x  = (const float*)d_in[0];
    const float* Wq = (const float*)d_in[1];
    const float* bq = (const float*)d_in[2];
    const float* Wk = (const float*)d_in[3];
    const float* bk = (const float*)d_in[4];
    const float* Wv = (const float*)d_in[5];
    const float* bv = (const float*)d_in[6];
    const float* Wo = (const float*)d_in[7];
    const float* bo = (const float*)d_in[8];
    float* out = (float*)d_out;

    char* ws = (char*)d_ws;
    bf16* xb  = (bf16*)(ws);                       // 16 MB
    bf16* Wqt = (bf16*)(ws + (16u << 20));         //  2 MB  ┐ contiguous
    bf16* Wkt = (bf16*)(ws + (18u << 20));         //  2 MB  │ [3072][1024]
    bf16* Wvt = (bf16*)(ws + (20u << 20));         //  2 MB  ┘ = Wall
    bf16* Wot = (bf16*)(ws + (22u << 20));         //  2 MB
    f16*  Q   = (f16*)(ws + (24u << 20));          // 16 MB
    f16*  K   = (f16*)(ws + (40u << 20));          // 16 MB
    f16*  Vt  = (f16*)(ws + (56u << 20));          // 16 MB (tiled V^T)
    bf16* y   = (bf16*)(ws + (72u << 20));         // 16 MB  (total 88 MB)

    dim3 gp(16, 16, 5);
    k_prep<<<gp, 256, 0, stream>>>(x, xb, Wq, Wk, Wv, Wo, Wqt, Wkt, Wvt, Wot);

    dim3 g1(32, 16);                     // 512 blocks = exactly 2/CU, balanced
    k_qkv_gemm<<<g1, 512, 0, stream>>>(xb, Wqt, bq, bk, bv, Q, K, Vt);

    dim3 g2(1024);                       // 1 q-tile/block, magic-square balance
    k_attn<<<g2, 256, 0, stream>>>(Q, K, Vt, y);

    dim3 g3(MTOK / 128, EMB / 128);
    k_out_gemm<<<g3, 256, 0, stream>>>(y, Wot, bo, out);
}

// Round 11
// 264.492 us; speedup vs baseline: 1.0608x; 1.0608x over previous
//
#include <hip/hip_runtime.h>

#define EMB   1024
#define NHEAD 16
#define HS    64
#define BATCH 4
#define SEQ   2048
#define MTOK  (BATCH*SEQ)   // 8192 tokens

typedef __bf16 bf16;
typedef __bf16 bf16x8 __attribute__((ext_vector_type(8)));
typedef __bf16 bf16x4 __attribute__((ext_vector_type(4)));
typedef float  f32x4  __attribute__((ext_vector_type(4)));
typedef _Float16 f16;
typedef f16 f16x4 __attribute__((ext_vector_type(4)));
typedef f16 f16x8 __attribute__((ext_vector_type(8)));

#define MFMA16(a,b,c)     __builtin_amdgcn_mfma_f32_16x16x32_bf16(a,b,c,0,0,0)
#define MFMA_H32(a,b,c)   __builtin_amdgcn_mfma_f32_16x16x32_f16(a,b,c,0,0,0)
#define MFMA_H16(a,b,c)   __builtin_amdgcn_mfma_f32_16x16x16f16(a,b,c,0,0,0)

#if __has_builtin(__builtin_amdgcn_exp2f)
#define EXP2(x) __builtin_amdgcn_exp2f(x)
#else
#define EXP2(x) exp2f(x)
#endif

// async global->LDS, 16B per lane; LDS dest = wave-uniform base + lane*16
#define GLL(g, l) __builtin_amdgcn_global_load_lds(                         \
        (const __attribute__((address_space(1))) void*)(g),                 \
        (__attribute__((address_space(3))) void*)(l), 16, 0, 0)

// ---------------- Stage 0: x convert + 4x weight transpose, one launch ------
__global__ __launch_bounds__(256) void k_prep(
        const float* __restrict__ x, bf16* __restrict__ xb,
        const float* __restrict__ W0, const float* __restrict__ W1,
        const float* __restrict__ W2, const float* __restrict__ W3,
        bf16* __restrict__ T0, bf16* __restrict__ T1,
        bf16* __restrict__ T2, bf16* __restrict__ T3) {
    const int z = blockIdx.z;
    if (z == 0) {                      // x fp32 -> bf16 (8M elements)
        const int blk = blockIdx.y * 16 + blockIdx.x;
        const size_t base = (size_t)blk * 32768;
        for (int j = threadIdx.x; j < 8192; j += 256) {
            size_t i = base + (size_t)j * 4;
            float4 v = *(const float4*)(x + i);
            bf16x4 o;
            o[0] = (bf16)v.x; o[1] = (bf16)v.y; o[2] = (bf16)v.z; o[3] = (bf16)v.w;
            *(bf16x4*)(xb + i) = o;
        }
        return;
    }
    __shared__ float tile[64][65];
    const float* W = (z == 1) ? W0 : (z == 2) ? W1 : (z == 3) ? W2 : W3;
    bf16* Wt = (z == 1) ? T0 : (z == 2) ? T1 : (z == 3) ? T2 : T3;
    int c0 = blockIdx.x * 64, r0 = blockIdx.y * 64;
    int tx = threadIdx.x & 63, ty = threadIdx.x >> 6;
    #pragma unroll
    for (int r = ty; r < 64; r += 4)
        tile[r][tx] = W[(r0 + r) * EMB + c0 + tx];
    __syncthreads();
    #pragma unroll
    for (int cc = ty; cc < 64; cc += 4)
        Wt[(c0 + cc) * EMB + r0 + tx] = (bf16)tile[tx][cc];
}

// ---------------- Stage 1: fused QKV GEMM, 256x192 tile, BK=32 --------------
// Q|K|V fused as one N=3072 GEMM, grid 32x16 = 512 blocks = exactly 2/CU.
// LDS 2x(16K A + 12K B) = 56KB. Waves 4Mx2N (64x96, acc[4][6]).
// Window schedule = round-5 proven structure (0 conflicts).
__global__ __launch_bounds__(512, 2) void k_qkv_gemm(
        const bf16* __restrict__ xb,
        const bf16* __restrict__ Wall,   // [3072][1024] = Wq^T | Wk^T | Wv^T
        const float* __restrict__ bq, const float* __restrict__ bk, const float* __restrict__ bv,
        f16* __restrict__ Q, f16* __restrict__ K, f16* __restrict__ Vt) {
    __shared__ __align__(16) bf16 As[2][8192];   // 2 x 16 KB (256 x 32)
    __shared__ __align__(16) bf16 Bs[2][6144];   // 2 x 12 KB (192 x 32)
    const int tid = threadIdx.x;
    const int lane = tid & 63;
    const int l15 = lane & 15, quad = lane >> 4;
    const int wave = tid >> 6;            // 0..7
    const int wm4 = wave & 3;             // M quarter: rows wm4*64..+63
    const int wn2 = wave >> 2;            // N half:   cols wn2*96..+95

    const int mt = blockIdx.x;            // 0..31 (x-major: B panel reused)
    const int nt = blockIdx.y;            // 0..15
    const int n0 = nt * 192;              // in [0,3072)

    const bf16* Abase = xb   + (size_t)mt * 256 * EMB;
    const bf16* Bbase = Wall + (size_t)n0 * EMB;

    // staging source swizzle: chunk n: pair-row P=n>>3, slot s=n&7 holds
    // source chunk c=s^(P&7) -> row 2P+(c>>2), k-chunk c&3.
    const int P   = tid >> 3, s8 = tid & 7;
    const int cch = s8 ^ (P & 7);
    const int r_  = 2 * P + (cch >> 2);
    const int kc8 = (cch & 3) * 8;
    const bf16* Asrc = Abase + (size_t)r_ * EMB + kc8;
    const bf16* Bsrc = Bbase + (size_t)r_ * EMB + kc8;

#define STAGE_A(T, cb) do {                                                  \
    GLL(Asrc + (T) * 32,             &As[cb][tid * 8]);                      \
    GLL(Asrc + 128 * EMB + (T) * 32, &As[cb][tid * 8 + 4096]); } while (0)
#define STAGE_B(T, cb) do {                                                  \
    GLL(Bsrc + (T) * 32,             &Bs[cb][tid * 8]);                      \
    if (tid < 256)                                                           \
        GLL(Bsrc + 128 * EMB + (T) * 32, &Bs[cb][tid * 8 + 4096]);           \
} while (0)

    // read offsets: frag row -> pair P=row>>1, h=row&1; slot (h*4+quad)^(P&7)
    int aoff[4], boff[6];
    #pragma unroll
    for (int mf = 0; mf < 4; mf++) {
        const int row = wm4 * 64 + mf * 16 + l15;
        const int Pr = row >> 1, hh = row & 1;
        aoff[mf] = Pr * 64 + ((((hh << 2) | quad)) ^ (Pr & 7)) * 8;
    }
    #pragma unroll
    for (int nf = 0; nf < 6; nf++) {
        const int row = wn2 * 96 + nf * 16 + l15;
        const int Pr = row >> 1, hh = row & 1;
        boff[nf] = Pr * 64 + ((((hh << 2) | quad)) ^ (Pr & 7)) * 8;
    }

    f32x4 acc[4][6];
    #pragma unroll
    for (int i = 0; i < 4; i++)
        #pragma unroll
        for (int j = 0; j < 6; j++) acc[i][j] = (f32x4){0.f, 0.f, 0.f, 0.f};

#define BARX __builtin_amdgcn_s_barrier()
#define PRI1 __builtin_amdgcn_s_setprio(1)
#define PRI0 __builtin_amdgcn_s_setprio(0)
#define SCHB __builtin_amdgcn_sched_barrier(0)
#define VM0 asm volatile("s_waitcnt vmcnt(0)" ::: "memory")

    // prologue: tile 0 into buf 0
    STAGE_A(0, 0); STAGE_B(0, 0);
    SCHB; VM0; BARX;

    bf16x8 a[4], b[3], b2[3];
    #pragma unroll 1
    for (int W = 0; W < 31; ++W) {
        const int c = W & 1;
        const bf16* Ab = As[c];
        const bf16* Bb = Bs[c];
        #pragma unroll
        for (int i = 0; i < 4; i++) a[i] = *(const bf16x8*)(Ab + aoff[i]);
        #pragma unroll
        for (int j = 0; j < 3; j++) b[j] = *(const bf16x8*)(Bb + boff[j]);
        STAGE_A(W + 1, c ^ 1);
        SCHB;
        BARX; PRI1;
        #pragma unroll
        for (int i = 0; i < 4; i++)
            #pragma unroll
            for (int j = 0; j < 3; j++)
                acc[i][j] = MFMA16(a[i], b[j], acc[i][j]);
        PRI0;
        #pragma unroll
        for (int j = 0; j < 3; j++) b2[j] = *(const bf16x8*)(Bb + boff[3 + j]);
        STAGE_B(W + 1, c ^ 1);
        SCHB; VM0; BARX;        // all waves' stage(W+1) landed; buf-c reads done
        PRI1;
        #pragma unroll
        for (int i = 0; i < 4; i++)
            #pragma unroll
            for (int j = 0; j < 3; j++)
                acc[i][3 + j] = MFMA16(a[i], b2[j], acc[i][3 + j]);
        PRI0;
    }
    {   // W = 31: buf 1, no staging, no gate
        const bf16* Ab = As[1];
        const bf16* Bb = Bs[1];
        #pragma unroll
        for (int i = 0; i < 4; i++) a[i] = *(const bf16x8*)(Ab + aoff[i]);
        #pragma unroll
        for (int j = 0; j < 3; j++) b[j]  = *(const bf16x8*)(Bb + boff[j]);
        #pragma unroll
        for (int j = 0; j < 3; j++) b2[j] = *(const bf16x8*)(Bb + boff[3 + j]);
        #pragma unroll
        for (int i = 0; i < 4; i++)
            #pragma unroll
            for (int j = 0; j < 3; j++) {
                acc[i][j]     = MFMA16(a[i], b[j],  acc[i][j]);
                acc[i][3 + j] = MFMA16(a[i], b2[j], acc[i][3 + j]);
            }
    }
#undef STAGE_A
#undef STAGE_B

    const float QSCALE = 0.18033688011112043f;   // 0.125 * log2(e)
    #pragma unroll
    for (int nf = 0; nf < 6; nf++) {
        const int col = n0 + wn2 * 96 + nf * 16 + l15;   // [0,3072)
        const int whichf = col >> 10;                    // wave-uniform per nf
        const int cc = col & 1023;
        const int h = cc >> 6, d = cc & 63;
        const float bv_ = (whichf == 0) ? bq[cc] : (whichf == 1) ? bk[cc] : bv[cc];
        if (whichf == 2) {
            #pragma unroll
            for (int mf = 0; mf < 4; mf++) {
                const int row0 = mt * 256 + wm4 * 64 + mf * 16 + quad * 4;
                const int b_ = row0 >> 11, tk0 = row0 & (SEQ - 1);
                f16x4 vv;
                #pragma unroll
                for (int r = 0; r < 4; r++) vv[r] = (f16)(acc[mf][nf][r] + bv_);
                *(f16x4*)(Vt + (((size_t)(b_ * NHEAD + h) * 32 + (tk0 >> 6)) * 64 + d) * 64
                          + (tk0 & 63)) = vv;
            }
        } else {
            f16* OUT = (whichf == 0) ? Q : K;
            const float scl = (whichf == 0) ? QSCALE : 1.0f;
            #pragma unroll
            for (int mf = 0; mf < 4; mf++) {
                const int row0 = mt * 256 + wm4 * 64 + mf * 16 + quad * 4;
                const int b_ = row0 >> 11, tk0 = row0 & (SEQ - 1);
                #pragma unroll
                for (int r = 0; r < 4; r++)
                    OUT[((size_t)(b_ * NHEAD + h) * SEQ + (tk0 + r)) * HS + d] =
                        (f16)((acc[mf][nf][r] + bv_) * scl);
            }
        }
    }
}

// ---------------- Stage 2: causal flash attention, S^T trick ----------------
// REVERTED to the round-5/7 LPT mapping (round-10 magic-square regressed:
// it placed near-heaviest q-tiles (qt=14,13) in the last 12% of dispatch
// order — anti-LPT tail. Dynamic LPT + backfill (LDS cap 5 blk/CU > 4 avg)
// beats static balance built on an unverified CU-assignment model.)
// One q-tile per block, 1024 blocks -> 4 blk/CU; XCD-pinned:
//   xcd = L&7, s = L>>3; bh = xcd*8 + (s&7); qt = 15 - (s>>3)  (LPT order)
__global__ __launch_bounds__(256) void k_attn(
        const f16* __restrict__ Q, const f16* __restrict__ K,
        const f16* __restrict__ Vt, bf16* __restrict__ y) {
    __shared__ __align__(16) f16 kbuf[2][64 * 64];   // 2 x 8 KB
    __shared__ __align__(16) f16 vbuf[2][64 * 64];   // 2 x 8 KB
    const int tid = threadIdx.x;
    const int wave = tid >> 6, lane = tid & 63;
    const int l15 = lane & 15, quad = lane >> 4;

    const int L = blockIdx.x;
    const int xcd = L & 7, s = L >> 3;
    const int bh = xcd * 8 + (s & 7);
    const int qt = 15 - (s >> 3);
    const int h = bh & (NHEAD - 1), b_ = bh >> 4;

    const f16* Qb = Q + (size_t)bh * SEQ * HS;
    const f16* Kb = K + (size_t)bh * SEQ * HS;
    const f16* Vb = Vt + (size_t)bh * 32 * 4096;

    const int c0 = tid, c1 = tid + 256;
    const int soff0 = (c0 >> 3) * 64 + (((c0 & 7) ^ ((c0 >> 3) & 7)) * 8);
    const int soff1 = (c1 >> 3) * 64 + (((c1 & 7) ^ ((c1 >> 3) & 7)) * 8);
    const int swz = l15 & 7;

    f16x4 ones;
    #pragma unroll
    for (int i = 0; i < 4; i++) ones[i] = (f16)1.0f;

    const int ntiles = 2 * qt + 2;
    const int qrow0 = qt * 128 + wave * 32;

    f16x8 qb[2][2];
    #pragma unroll
    for (int qf = 0; qf < 2; qf++)
        #pragma unroll
        for (int dk = 0; dk < 2; dk++)
            qb[qf][dk] = *(const f16x8*)(Qb + (qrow0 + 16 * qf + l15) * HS + 32 * dk + quad * 8);

    f32x4 o[2][4], lacc[2];
    #pragma unroll
    for (int qf = 0; qf < 2; qf++) {
        lacc[qf] = (f32x4){0.f, 0.f, 0.f, 0.f};
        #pragma unroll
        for (int df = 0; df < 4; df++) o[qf][df] = (f32x4){0.f, 0.f, 0.f, 0.f};
    }

    f16x8 kr0 = *(const f16x8*)(Kb + c0 * 8);
    f16x8 kr1 = *(const f16x8*)(Kb + c1 * 8);
    f16x8 vr0 = *(const f16x8*)(Vb + c0 * 8);
    f16x8 vr1 = *(const f16x8*)(Vb + c1 * 8);
    *(f16x8*)(kbuf[0] + soff0) = kr0;
    *(f16x8*)(kbuf[0] + soff1) = kr1;
    *(f16x8*)(vbuf[0] + soff0) = vr0;
    *(f16x8*)(vbuf[0] + soff1) = vr1;

    for (int it = 0; it < ntiles; ++it) {
        const int kv0 = it * 64;
        __syncthreads();
        if (it + 1 < ntiles) {
            const f16* kg = Kb + (size_t)(kv0 + 64) * HS;
            const f16* vg = Vb + (size_t)(it + 1) * 4096;
            kr0 = *(const f16x8*)(kg + c0 * 8);
            kr1 = *(const f16x8*)(kg + c1 * 8);
            vr0 = *(const f16x8*)(vg + c0 * 8);
            vr1 = *(const f16x8*)(vg + c1 * 8);
        }
        if (kv0 <= qrow0 + 31) {
            const f16* kb_ = kbuf[it & 1];
            const f16* vb_ = vbuf[it & 1];

            f32x4 sreg[4][2];
            #pragma unroll
            for (int mb = 0; mb < 4; mb++) {
                f16x8 ka0 = *(const f16x8*)(kb_ + (16 * mb + l15) * 64 + ((quad ^ swz) * 8));
                f16x8 ka1 = *(const f16x8*)(kb_ + (16 * mb + l15) * 64 + (((4 + quad) ^ swz) * 8));
                #pragma unroll
                for (int qf = 0; qf < 2; qf++) {
                    f32x4 t = (f32x4){0.f, 0.f, 0.f, 0.f};
                    t = MFMA_H32(ka0, qb[qf][0], t);
                    t = MFMA_H32(ka1, qb[qf][1], t);
                    sreg[mb][qf] = t;
                }
            }

            f16x4 pa[4][2];
            const bool edge = (kv0 + 63 > qrow0);
            #pragma unroll
            for (int mb = 0; mb < 4; mb++)
                #pragma unroll
                for (int qf = 0; qf < 2; qf++) {
                    f16x4 p;
                    if (edge) {
                        #pragma unroll
                        for (int r = 0; r < 4; r++) {
                            const int kvc = kv0 + 16 * mb + quad * 4 + r;
                            const int qq  = qrow0 + 16 * qf + l15;
                            p[r] = (f16)((kvc <= qq) ? EXP2(sreg[mb][qf][r]) : 0.f);
                        }
                    } else {
                        #pragma unroll
                        for (int r = 0; r < 4; r++)
                            p[r] = (f16)EXP2(sreg[mb][qf][r]);
                    }
                    pa[mb][qf] = p;
                }

            #pragma unroll
            for (int df = 0; df < 4; df++)
                #pragma unroll
                for (int kb = 0; kb < 4; kb++) {
                    f16x4 vfrag = *(const f16x4*)(vb_ + (16 * df + l15) * 64 +
                                    (((2 * kb + (quad >> 1)) ^ swz) * 8) + (quad & 1) * 4);
                    #pragma unroll
                    for (int qf = 0; qf < 2; qf++)
                        o[qf][df] = MFMA_H16(pa[kb][qf], vfrag, o[qf][df]);
                }
            #pragma unroll
            for (int kb = 0; kb < 4; kb++)
                #pragma unroll
                for (int qf = 0; qf < 2; qf++)
                    lacc[qf] = MFMA_H16(pa[kb][qf], ones, lacc[qf]);
        }
        if (it + 1 < ntiles) {
            const int nb = (it + 1) & 1;
            *(f16x8*)(kbuf[nb] + soff0) = kr0;
            *(f16x8*)(kbuf[nb] + soff1) = kr1;
            *(f16x8*)(vbuf[nb] + soff0) = vr0;
            *(f16x8*)(vbuf[nb] + soff1) = vr1;
        }
    }

    #pragma unroll
    for (int qf = 0; qf < 2; qf++)
        #pragma unroll
        for (int r = 0; r < 4; r++) {
            float inv = 1.f / lacc[qf][r];
            int t = qrow0 + 16 * qf + quad * 4 + r;
            bf16* yp = y + ((size_t)(b_ * SEQ + t)) * EMB + h * HS;
            #pragma unroll
            for (int df = 0; df < 4; df++)
                yp[df * 16 + l15] = (bf16)(o[qf][df][r] * inv);
        }
}

// ---------------- Stage 3: out projection (BK=64, swizzled, fp32 out) -------
// Round-7 m97-style loop (r9's r5-port regressed: 2x barriers for 8-MFMA
// phases costs more than the schedule gains at this 128x128/K=1024 shape).
__global__ __launch_bounds__(256) void k_out_gemm(
        const bf16* __restrict__ y, const bf16* __restrict__ Wot,
        const float* __restrict__ bo, float* __restrict__ out) {
    __shared__ __align__(16) bf16 As[128 * 64];
    __shared__ __align__(16) bf16 Bs[128 * 64];
    const int tid = threadIdx.x;
    const int lane = tid & 63;
    const int wave = tid >> 6;
    const int l15 = lane & 15, quad = lane >> 4;
    const int wm = (wave >> 1) * 64, wn = (wave & 1) * 64;
    const int m0 = blockIdx.x * 128;
    const int n0 = blockIdx.y * 128;

    f32x4 acc[4][4];
    #pragma unroll
    for (int i = 0; i < 4; i++)
        #pragma unroll
        for (int j = 0; j < 4; j++) acc[i][j] = (f32x4){0.f, 0.f, 0.f, 0.f};

    const int r0_ = tid >> 3;
    const int kcs = ((tid & 7) ^ (r0_ & 7)) * 8;
    const bf16* Ag = y   + (size_t)m0 * EMB + r0_ * EMB + kcs;
    const bf16* Bg = Wot + (size_t)n0 * EMB + r0_ * EMB + kcs;
    const int rsw = l15 & 7;

    for (int k0 = 0; k0 < EMB; k0 += 64) {
        __syncthreads();
        #pragma unroll
        for (int g = 0; g < 4; g++) {
            GLL(Ag + 32 * g * EMB + k0, As + (tid + g * 256) * 8);
            GLL(Bg + 32 * g * EMB + k0, Bs + (tid + g * 256) * 8);
        }
        __syncthreads();

        bf16x8 af[2][4], bfr[2][4];
        #pragma unroll
        for (int h = 0; h < 2; h++) {
            #pragma unroll
            for (int rf = 0; rf < 4; rf++)
                af[h][rf] = *(const bf16x8*)(As + (wm + rf * 16 + l15) * 64 +
                                             (((4 * h + quad) ^ rsw) * 8));
            #pragma unroll
            for (int cf = 0; cf < 4; cf++)
                bfr[h][cf] = *(const bf16x8*)(Bs + (wn + cf * 16 + l15) * 64 +
                                              (((4 * h + quad) ^ rsw) * 8));
        }
        #pragma unroll
        for (int h = 0; h < 2; h++)
            #pragma unroll
            for (int rf = 0; rf < 4; rf++)
                #pragma unroll
                for (int cf = 0; cf < 4; cf++)
                    acc[rf][cf] = MFMA16(af[h][rf], bfr[h][cf], acc[rf][cf]);
    }

    #pragma unroll
    for (int cf = 0; cf < 4; cf++) {
        const int col = n0 + wn + cf * 16 + l15;
        const float bv_ = bo[col];
        #pragma unroll
        for (int rf = 0; rf < 4; rf++) {
            #pragma unroll
            for (int r = 0; r < 4; r++) {
                const int row = m0 + wm + rf * 16 + quad * 4 + r;
                out[(size_t)row * EMB + col] = acc[rf][cf][r] + bv_;
            }
        }
    }
}

extern "C" void kernel_launch(void* const* d_in, const int* in_sizes, int n_in,
                              void* d_out, int out_size, void* d_ws, size_t ws_size,
                              hipStream_t stream) {
    const float* x  = (const float*)d_in[0];
    const float* Wq = (const float*)d_in[1];
    const float* bq = (const float*)d_in[2];
    const float* Wk = (const float*)d_in[3];
    const float* bk = (const float*)d_in[4];
    const float* Wv = (const float*)d_in[5];
    const float* bv = (const float*)d_in[6];
    const float* Wo = (const float*)d_in[7];
    const float* bo = (const float*)d_in[8];
    float* out = (float*)d_out;

    char* ws = (char*)d_ws;
    bf16* xb  = (bf16*)(ws);                       // 16 MB
    bf16* Wqt = (bf16*)(ws + (16u << 20));         //  2 MB  ┐ contiguous
    bf16* Wkt = (bf16*)(ws + (18u << 20));         //  2 MB  │ [3072][1024]
    bf16* Wvt = (bf16*)(ws + (20u << 20));         //  2 MB  ┘ = Wall
    bf16* Wot = (bf16*)(ws + (22u << 20));         //  2 MB
    f16*  Q   = (f16*)(ws + (24u << 20));          // 16 MB
    f16*  K   = (f16*)(ws + (40u << 20));          // 16 MB
    f16*  Vt  = (f16*)(ws + (56u << 20));          // 16 MB (tiled V^T)
    bf16* y   = (bf16*)(ws + (72u << 20));         // 16 MB  (total 88 MB)

    dim3 gp(16, 16, 5);
    k_prep<<<gp, 256, 0, stream>>>(x, xb, Wq, Wk, Wv, Wo, Wqt, Wkt, Wvt, Wot);

    dim3 g1(32, 16);                     // 512 blocks = exactly 2/CU, balanced
    k_qkv_gemm<<<g1, 512, 0, stream>>>(xb, Wqt, bq, bk, bv, Q, K, Vt);

    dim3 g2(1024);                       // 1 q-tile/block, XCD-locality + LPT
    k_attn<<<g2, 256, 0, stream>>>(Q, K, Vt, y);

    dim3 g3(MTOK / 128, EMB / 128);
    k_out_gemm<<<g3, 256, 0, stream>>>(y, Wot, bo, out);
}